// Round 9
// baseline (283.621 us; speedup 1.0000x reference)
//
#include <hip/hip_runtime.h>

#define CDIM 128
#define NC   8388608

// ws layout (float offsets): nrm @0 (960) | DT @1024 (122880) | keys @131072 (262144 ints) | partials @393216

// ---- kernel 0: column norms + transposed dict copies ----
__global__ void vq_prep(const float* __restrict__ D0, const float* __restrict__ D1,
                        const float* __restrict__ D2, const float* __restrict__ D3,
                        float* __restrict__ nrm, float* __restrict__ DT) {
  int g = blockIdx.x * 256 + threadIdx.x;
  if (g >= 960) return;
  const float* D; int K, k; float* T;
  if (g < 64)       { D = D0; K = 64;  k = g;       T = DT; }
  else if (g < 192) { D = D1; K = 128; k = g - 64;  T = DT + 8192; }
  else if (g < 448) { D = D2; K = 256; k = g - 192; T = DT + 24576; }
  else              { D = D3; K = 512; k = g - 448; T = DT + 57344; }
  float s = 0.f;
  for (int c = 0; c < 128; ++c) { float v = D[c*K+k]; s = fmaf(v,v,s); T[k*128+c] = v; }
  nrm[g] = s;
}

// prefetch one [128 c][64 col] dict tile into 8 named float4 regs (half-block g owns one tile)
#define PF(DA, KA, TBA, DB, KB, TBB) { \
  const float* __restrict__ Dg = g ? (DB) : (DA); \
  const int Kg = g ? (KB) : (KA); \
  const float* __restrict__ pfb = Dg + c0s * Kg + (g ? (TBB) : (TBA)) + col4 * 4; \
  p0 = *(const float4*)(pfb); \
  p1 = *(const float4*)(pfb + 16 * Kg); \
  p2 = *(const float4*)(pfb + 32 * Kg); \
  p3 = *(const float4*)(pfb + 48 * Kg); \
  p4 = *(const float4*)(pfb + 64 * Kg); \
  p5 = *(const float4*)(pfb + 80 * Kg); \
  p6 = *(const float4*)(pfb + 96 * Kg); \
  p7 = *(const float4*)(pfb + 112 * Kg); }

// write prefetched tile to its sd slot; 16-lane passes each cover one full 256-B row -> conflict-free
#define STORE_SD() { \
  *(float4*)(sw + 0)    = p0; *(float4*)(sw + 1024) = p1; \
  *(float4*)(sw + 2048) = p2; *(float4*)(sw + 3072) = p3; \
  *(float4*)(sw + 4096) = p4; *(float4*)(sw + 5120) = p5; \
  *(float4*)(sw + 6144) = p6; *(float4*)(sw + 7168) = p7; }

#define FMAS(XV0, XV1, DV) \
  a0.x=fmaf(XV0.x,DV.x,a0.x); a0.y=fmaf(XV0.x,DV.y,a0.y); a0.z=fmaf(XV0.x,DV.z,a0.z); a0.w=fmaf(XV0.x,DV.w,a0.w); \
  a1.x=fmaf(XV0.y,DV.x,a1.x); a1.y=fmaf(XV0.y,DV.y,a1.y); a1.z=fmaf(XV0.y,DV.z,a1.z); a1.w=fmaf(XV0.y,DV.w,a1.w); \
  a2.x=fmaf(XV0.z,DV.x,a2.x); a2.y=fmaf(XV0.z,DV.y,a2.y); a2.z=fmaf(XV0.z,DV.z,a2.z); a2.w=fmaf(XV0.z,DV.w,a2.w); \
  a3.x=fmaf(XV0.w,DV.x,a3.x); a3.y=fmaf(XV0.w,DV.y,a3.y); a3.z=fmaf(XV0.w,DV.z,a3.z); a3.w=fmaf(XV0.w,DV.w,a3.w); \
  a4.x=fmaf(XV1.x,DV.x,a4.x); a4.y=fmaf(XV1.x,DV.y,a4.y); a4.z=fmaf(XV1.x,DV.z,a4.z); a4.w=fmaf(XV1.x,DV.w,a4.w); \
  a5.x=fmaf(XV1.y,DV.x,a5.x); a5.y=fmaf(XV1.y,DV.y,a5.y); a5.z=fmaf(XV1.y,DV.z,a5.z); a5.w=fmaf(XV1.y,DV.w,a5.w); \
  a6.x=fmaf(XV1.z,DV.x,a6.x); a6.y=fmaf(XV1.z,DV.y,a6.y); a6.z=fmaf(XV1.z,DV.z,a6.z); a6.w=fmaf(XV1.z,DV.w,a6.w); \
  a7.x=fmaf(XV1.w,DV.x,a7.x); a7.y=fmaf(XV1.w,DV.y,a7.y); a7.z=fmaf(XV1.w,DV.z,a7.z); a7.w=fmaf(XV1.w,DV.w,a7.w);

// one c-step: 8 rows (2 xt b128, xor-swizzled) x 4 cols (1 sd b128) = 32 FMA
#define KSTEP(KOFF, SOFF) { \
  float4 xv0 = *(const float4*)(xtb + (o + (KOFF))); \
  float4 xv1 = *(const float4*)(xtb + ((o + (KOFF)) ^ 16u)); \
  float4 dv  = *(const float4*)(sb + (SOFF)); \
  FMAS(xv0, xv1, dv) }

// per-row criterion over 4 ascending cols (strict < keeps lowest col)
#define ROWC(BJ, KJ, AJ) { \
  BJ = fmaf(-2.f, AJ.x, nv.x); KJ = cg0; \
  float cr_; \
  cr_ = fmaf(-2.f, AJ.y, nv.y); if (cr_ < BJ) { BJ = cr_; KJ = cg0 + 1; } \
  cr_ = fmaf(-2.f, AJ.z, nv.z); if (cr_ < BJ) { BJ = cr_; KJ = cg0 + 2; } \
  cr_ = fmaf(-2.f, AJ.w, nv.w); if (cr_ < BJ) { BJ = cr_; KJ = cg0 + 3; } }

// lex-min butterfly over the 8 lc-lanes
#define SH3(BJ, KJ) { \
  { float pb_ = __shfl_xor(BJ, 1); int pk_ = __shfl_xor(KJ, 1); \
    if (pb_ < BJ || (pb_ == BJ && pk_ < KJ)) { BJ = pb_; KJ = pk_; } } \
  { float pb_ = __shfl_xor(BJ, 2); int pk_ = __shfl_xor(KJ, 2); \
    if (pb_ < BJ || (pb_ == BJ && pk_ < KJ)) { BJ = pb_; KJ = pk_; } } \
  { float pb_ = __shfl_xor(BJ, 4); int pk_ = __shfl_xor(KJ, 4); \
    if (pb_ < BJ || (pb_ == BJ && pk_ < KJ)) { BJ = pb_; KJ = pk_; } } }

#define COMPUTE(TBA, NFA, TBB, NFB) { \
  const int tbr   = ts ? (TBB) : (TBA); \
  const int nbase = (ts ? (NFB) + (TBB) : (NFA) + (TBA)) + cbase; \
  float4 z4 = make_float4(0.f, 0.f, 0.f, 0.f); \
  float4 a0 = z4, a1 = z4, a2 = z4, a3 = z4, a4 = z4, a5 = z4, a6 = z4, a7 = z4; \
  _Pragma("unroll 2") \
  for (int c4 = 0; c4 < 32; ++c4) { \
    const unsigned o = (((unsigned)c4 * 2048u) + rb4q) ^ ((unsigned)(c4 & 7) << 4); \
    const float* sb = sdp + c4 * 256 + cbase; \
    KSTEP(0u, 0) KSTEP(512u, 64) KSTEP(1024u, 128) KSTEP(1536u, 192) \
  } \
  const float4 nv = *(const float4*)(nrm_s + nbase); \
  const int cg0 = tbr + cbase; \
  float b0_, b1_, b2_, b3_, b4_, b5_, b6_, b7_; \
  int   k0_, k1_, k2_, k3_, k4_, k5_, k6_, k7_; \
  ROWC(b0_, k0_, a0) ROWC(b1_, k1_, a1) ROWC(b2_, k2_, a2) ROWC(b3_, k3_, a3) \
  ROWC(b4_, k4_, a4) ROWC(b5_, k5_, a5) ROWC(b6_, k6_, a6) ROWC(b7_, k7_, a7) \
  SH3(b0_, k0_) SH3(b1_, k1_) SH3(b2_, k2_) SH3(b3_, k3_) \
  SH3(b4_, k4_) SH3(b5_, k5_) SH3(b6_, k6_) SH3(b7_, k7_) \
  if (lc == 0) { \
    cand2[w][lr*8+0] = make_float2(b0_, __int_as_float(k0_)); \
    cand2[w][lr*8+1] = make_float2(b1_, __int_as_float(k1_)); \
    cand2[w][lr*8+2] = make_float2(b2_, __int_as_float(k2_)); \
    cand2[w][lr*8+3] = make_float2(b3_, __int_as_float(k3_)); \
    cand2[w][lr*8+4] = make_float2(b4_, __int_as_float(k4_)); \
    cand2[w][lr*8+5] = make_float2(b5_, __int_as_float(k5_)); \
    cand2[w][lr*8+6] = make_float2(b6_, __int_as_float(k6_)); \
    cand2[w][lr*8+7] = make_float2(b7_, __int_as_float(k7_)); } }

#define LX(BB, KK, C2) { int kq_ = __float_as_int(C2.y); \
  if (C2.x < BB || (C2.x == BB && kq_ < KK)) { BB = C2.x; KK = kq_; } }

// merge previous round's cand2 into the per-dict running best (thread t owns row t; no races)
#define MERGEPREV(DPA, DPB) if (t < 128) { \
  const int rs_ = t >> 6, rr_ = t & 63; \
  { float2 c0m = cand2[rs_*4+0][rr_]; \
    float bb = c0m.x; int kk = __float_as_int(c0m.y); \
    float2 c1m = cand2[rs_*4+2][rr_]; LX(bb, kk, c1m) \
    float2 ro = rb[DPA][t]; int ko = __float_as_int(ro.y); \
    if (bb < ro.x || (bb == ro.x && kk < ko)) rb[DPA][t] = make_float2(bb, __int_as_float(kk)); } \
  { float2 c0m = cand2[rs_*4+1][rr_]; \
    float bb = c0m.x; int kk = __float_as_int(c0m.y); \
    float2 c1m = cand2[rs_*4+3][rr_]; LX(bb, kk, c1m) \
    float2 ro = rb[DPB][t]; int ko = __float_as_int(ro.y); \
    if (bb < ro.x || (bb == ro.x && kk < ko)) rb[DPB][t] = make_float2(bb, __int_as_float(kk)); } }

#define NOMRG ((void)0)

#define ROUND(TBA, NFA, TBB, NFB, MRG, NDA, NKA, NTBA, NDB, NKB, NTBB) \
  __syncthreads(); \
  STORE_SD(); \
  MRG; \
  PF(NDA, NKA, NTBA, NDB, NKB, NTBB); \
  __syncthreads(); \
  COMPUTE(TBA, NFA, TBB, NFB)

// ---- kernel 1: 512 thr, 128 rows/block, 8x4 microtile, dual-tile rounds ----
__global__ __launch_bounds__(512, 1) void vq_main(
    const float* __restrict__ x,
    const float* __restrict__ D0, const float* __restrict__ D1,
    const float* __restrict__ D2, const float* __restrict__ D3,
    const float* __restrict__ nrm, int* __restrict__ keys)
{
  __shared__ float  xt[16384];      // [c][128 rows], xor-swizzled, 64 KB
  __shared__ float  sdbuf[2][8192]; // two [128][64] tiles, 64 KB
  __shared__ float2 cand2[8][64];   // per-wave per-row tile winners
  __shared__ float2 rb[4][128];     // running best per (dict, row)
  __shared__ float  nrm_s[960];

  const int t = threadIdx.x;
  const int w = t >> 6, l = t & 63;
  const int rset = w >> 2;            // row-set (rows rset*64..+63)
  const int half = (w >> 1) & 1;      // col half within tile
  const int ts   = w & 1;             // tile slot A/B
  const int lr = l >> 3, lc = l & 7;
  const unsigned rb4q = (unsigned)((rset * 64 + lr * 8) * 4);  // byte offset of lane's 8 rows
  const int cbase = half * 32 + lc * 4;                        // lane's 4 cols within tile
  const int u = t & 255, g = t >> 8;  // staging: half-block g stages tile g
  const int c0s = u >> 4, col4 = u & 15;
  const float* __restrict__ sdp = sdbuf[ts];
  float* sw = sdbuf[g] + c0s * 64 + col4 * 4;
  const char* xtb = (const char*)xt;

  if (t < 480) ((float2*)nrm_s)[t] = ((const float2*)nrm)[t];
  if (t < 128) {
    float2 ini = make_float2(1e30f, 0.f);
    rb[0][t] = ini; rb[1][t] = ini; rb[2][t] = ini; rb[3][t] = ini;
  }
  // stage x transposed + swizzled: [row][c] global -> [c][row] LDS
  {
    const float4* __restrict__ xg = (const float4*)x + (size_t)blockIdx.x * 4096;
    #pragma unroll
    for (int j = 0; j < 8; ++j) {
      const int f = j * 512 + t;
      const float4 v = xg[f];
      const int row = f >> 5;
      const unsigned c0 = (unsigned)(f & 31) * 4u;
      const unsigned sz = ((c0 >> 2) & 7u) << 4;
      float* bptr = (float*)((char*)xt + (((c0 * 128u + (unsigned)row) * 4u) ^ sz));
      bptr[0] = v.x; bptr[128] = v.y; bptr[256] = v.z; bptr[384] = v.w;
    }
  }
  float4 p0, p1, p2, p3, p4, p5, p6, p7;
  PF(D0, 64, 0, D1, 128, 0);

  // rounds: (tileA, tileB) per round; dicts compile-time; last tile duplicated (idempotent)
  ROUND(  0,   0,   0,  64, NOMRG,            D1, 128,  64, D2, 256,   0);
  ROUND( 64,  64,   0, 192, MERGEPREV(0, 1),  D2, 256,  64, D2, 256, 128);
  ROUND( 64, 192, 128, 192, MERGEPREV(1, 2),  D2, 256, 192, D3, 512,   0);
  ROUND(192, 192,   0, 448, MERGEPREV(2, 2),  D3, 512,  64, D3, 512, 128);
  ROUND( 64, 448, 128, 448, MERGEPREV(2, 3),  D3, 512, 192, D3, 512, 256);
  ROUND(192, 448, 256, 448, MERGEPREV(3, 3),  D3, 512, 320, D3, 512, 384);
  ROUND(320, 448, 384, 448, MERGEPREV(3, 3),  D3, 512, 448, D3, 512, 448);
  ROUND(448, 448, 448, 448, MERGEPREV(3, 3),  D3, 512, 448, D3, 512, 448);

  __syncthreads();
  MERGEPREV(3, 3)
  if (t < 128) {
    const int rg = (blockIdx.x * 128 + t) << 2;
    keys[rg]     = __float_as_int(rb[0][t].y);
    keys[rg | 1] = __float_as_int(rb[1][t].y);
    keys[rg | 2] = __float_as_int(rb[2][t].y);
    keys[rg | 3] = __float_as_int(rb[3][t].y);
  }
}

// ---- kernel 2: gather winners (coalesced via DT), write out + loss partials ----
__global__ __launch_bounds__(256, 8) void vq_merge(
    const float* __restrict__ x, const float* __restrict__ DT,
    const int* __restrict__ keys,
    const float* __restrict__ alpha_p, const float* __restrict__ gamma_p,
    float* __restrict__ out, float* __restrict__ partials)
{
  __shared__ int kk[2][4];
  __shared__ float wr[4];
  const int t = threadIdx.x;
  const int c = t & 127, rs = t >> 7;
  const int row0 = blockIdx.x * 2;
  if (t < 8) {
    int r = t >> 2, d = t & 3;
    kk[r][d] = keys[((row0 + r) << 2) | d];
  }
  __syncthreads();
  const int row = row0 + rs;
  const float a = alpha_p[0];
  const float g0 = gamma_p[0], g1 = gamma_p[1], g2 = gamma_p[2], g3 = gamma_p[3];
  const float xv = x[(size_t)row * CDIM + c];
  const float d0 = DT[         kk[rs][0] * 128 + c];
  const float d1 = DT[ 8192  + kk[rs][1] * 128 + c];
  const float d2 = DT[ 24576 + kk[rs][2] * 128 + c];
  const float d3 = DT[ 57344 + kk[rs][3] * 128 + c];
  out[(size_t)row * CDIM + c] = a * (g0*d0 + g1*d1 + g2*d2 + g3*d3);
  float e0 = fmaf(-a, d0, xv), e1 = fmaf(-a, d1, xv);
  float e2 = fmaf(-a, d2, xv), e3 = fmaf(-a, d3, xv);
  float lc = g0*e0*e0 + g1*e1*e1 + g2*e2*e2 + g3*e3*e3;
  #pragma unroll
  for (int off = 32; off > 0; off >>= 1) lc += __shfl_down(lc, off);
  if ((t & 63) == 0) wr[t >> 6] = lc;
  __syncthreads();
  if (t == 0) partials[blockIdx.x] = wr[0] + wr[1] + wr[2] + wr[3];
}

// ---- kernel 3: final deterministic loss reduction ----
__global__ void vq_loss(const float* __restrict__ partials, float* __restrict__ lossp) {
  __shared__ float wr[4];
  const int t = threadIdx.x;
  float v = 0.f;
  #pragma unroll 8
  for (int i = 0; i < 128; ++i) v += partials[i * 256 + t];
  #pragma unroll
  for (int off = 32; off > 0; off >>= 1) v += __shfl_down(v, off);
  if ((t & 63) == 0) wr[t >> 6] = v;
  __syncthreads();
  if (t == 0) lossp[0] = (wr[0] + wr[1] + wr[2] + wr[3]) * (1.25f / 8388608.f);
}

extern "C" void kernel_launch(void* const* d_in, const int* in_sizes, int n_in,
                              void* d_out, int out_size, void* d_ws, size_t ws_size,
                              hipStream_t stream) {
  const float* x  = (const float*)d_in[0];
  const float* D0 = (const float*)d_in[1];
  const float* D1 = (const float*)d_in[2];
  const float* D2 = (const float*)d_in[3];
  const float* D3 = (const float*)d_in[4];
  const float* alpha = (const float*)d_in[5];
  const float* gamma = (const float*)d_in[6];
  float* out = (float*)d_out;

  float* ws = (float*)d_ws;
  float* nrm = ws;                        // 960
  float* DT  = ws + 1024;                 // 122880
  int*  keys = (int*)(ws + 131072);       // 262144 ints
  float* partials = ws + 393216;          // 32768

  vq_prep<<<4, 256, 0, stream>>>(D0, D1, D2, D3, nrm, DT);
  vq_main<<<512, 512, 0, stream>>>(x, D0, D1, D2, D3, nrm, keys);
  vq_merge<<<32768, 256, 0, stream>>>(x, DT, keys, alpha, gamma, out, partials);
  vq_loss<<<1, 256, 0, stream>>>(partials, out + NC);
}

// Round 10
// 264.972 us; speedup vs baseline: 1.0704x; 1.0704x over previous
//
#include <hip/hip_runtime.h>

#define CDIM 128
#define NC   8388608

typedef __attribute__((ext_vector_type(8)))  short bf8v;   // 8 bf16 (4 VGPRs)
typedef __attribute__((ext_vector_type(16))) float f32x16; // MFMA 32x32 acc

// ws layout (float offsets):
//   nrm  @0       (1024)
//   DT   @1024    (122880)
//   Bph  @123904  (61440)   [30 tiles][8 chunks][64 lanes] x 16B bf16-hi
//   Bpl  @185344  (61440)   same, bf16-lo
//   keys @246784  (262144 ints)
//   partials @508928 (32768)

__device__ __forceinline__ void bsplit(float v, short& h, short& lo) {
  unsigned u = __float_as_uint(v);
  unsigned hb = (u + 0x7fffu + ((u >> 16) & 1u)) >> 16;   // RNE to bf16
  float hf = __uint_as_float(hb << 16);
  float lf = v - hf;
  unsigned u2 = __float_as_uint(lf);
  unsigned lb = (u2 + 0x7fffu + ((u2 >> 16) & 1u)) >> 16;
  h = (short)hb; lo = (short)lb;
}

// ---- kernel 0: column norms + transposed fp32 dict copies (exact, for gather) ----
__global__ void vq_prep(const float* __restrict__ D0, const float* __restrict__ D1,
                        const float* __restrict__ D2, const float* __restrict__ D3,
                        float* __restrict__ nrm, float* __restrict__ DT) {
  int g = blockIdx.x * 256 + threadIdx.x;
  if (g >= 960) return;
  const float* D; int K, k; float* T;
  if (g < 64)       { D = D0; K = 64;  k = g;       T = DT; }
  else if (g < 192) { D = D1; K = 128; k = g - 64;  T = DT + 8192; }
  else if (g < 448) { D = D2; K = 256; k = g - 192; T = DT + 24576; }
  else              { D = D3; K = 512; k = g - 448; T = DT + 57344; }
  float s = 0.f;
  for (int c = 0; c < 128; ++c) { float v = D[c*K+k]; s = fmaf(v,v,s); T[k*128+c] = v; }
  nrm[g] = s;
}

// ---- kernel 1: pack dicts into MFMA B-fragment order, bf16 hi/lo ----
// entry g = (T*8 + c)*64 + lane: 8 bf16 = B[k0+j][col], col = T*32+(l&31), k0 = 16c+8*(l>>5)
__global__ void vq_pack(const float* __restrict__ D0, const float* __restrict__ D1,
                        const float* __restrict__ D2, const float* __restrict__ D3,
                        bf8v* __restrict__ Bph, bf8v* __restrict__ Bpl) {
  int g = blockIdx.x * 256 + threadIdx.x;           // 60*256 = 15360 exact
  int T = g >> 9, c = (g >> 6) & 7, l = g & 63;
  int col = T * 32 + (l & 31);
  int k0 = c * 16 + (l >> 5) * 8;
  const float* D; int K, cb;
  if (col < 64)       { D = D0; K = 64;  cb = col; }
  else if (col < 192) { D = D1; K = 128; cb = col - 64; }
  else if (col < 448) { D = D2; K = 256; cb = col - 192; }
  else                { D = D3; K = 512; cb = col - 448; }
  short h0,h1,h2,h3,h4,h5,h6,h7, q0,q1,q2,q3,q4,q5,q6,q7;
  bsplit(D[(k0+0)*K + cb], h0, q0);
  bsplit(D[(k0+1)*K + cb], h1, q1);
  bsplit(D[(k0+2)*K + cb], h2, q2);
  bsplit(D[(k0+3)*K + cb], h3, q3);
  bsplit(D[(k0+4)*K + cb], h4, q4);
  bsplit(D[(k0+5)*K + cb], h5, q5);
  bsplit(D[(k0+6)*K + cb], h6, q6);
  bsplit(D[(k0+7)*K + cb], h7, q7);
  Bph[g] = (bf8v){h0,h1,h2,h3,h4,h5,h6,h7};
  Bpl[g] = (bf8v){q0,q1,q2,q3,q4,q5,q6,q7};
}

#define MK8(U0, U1, HD, LD) { \
  short h0,h1,h2,h3,h4,h5,h6,h7, q0,q1,q2,q3,q4,q5,q6,q7; \
  bsplit(U0.x,h0,q0); bsplit(U0.y,h1,q1); bsplit(U0.z,h2,q2); bsplit(U0.w,h3,q3); \
  bsplit(U1.x,h4,q4); bsplit(U1.y,h5,q5); bsplit(U1.z,h6,q6); bsplit(U1.w,h7,q7); \
  HD = (bf8v){h0,h1,h2,h3,h4,h5,h6,h7}; \
  LD = (bf8v){q0,q1,q2,q3,q4,q5,q6,q7}; }

#define MFMA_B(AC, AF, BF) AC = __builtin_amdgcn_mfma_f32_32x32x16_bf16((AF), (BF), (AC), 0, 0, 0)

#define TILE_COMPUTE(T) { \
  f32x16 ae0 = zero16, ao0 = zero16, ae1 = zero16, ao1 = zero16; \
  _Pragma("unroll") \
  for (int cp = 0; cp < 4; ++cp) { \
    const int ce = 2*cp, co = 2*cp+1; \
    bf8v bhe = BhL[ce*64 + l]; \
    bf8v bho = BhL[co*64 + l]; \
    bf8v ble = BlL[ce*64 + l]; \
    bf8v blo = BlL[co*64 + l]; \
    MFMA_B(ae0, Ah0[ce], bhe); MFMA_B(ao0, Ah0[co], bho); \
    MFMA_B(ae1, Ah1[ce], bhe); MFMA_B(ao1, Ah1[co], bho); \
    MFMA_B(ae0, Al0[ce], bhe); MFMA_B(ao0, Al0[co], bho); \
    MFMA_B(ae1, Al1[ce], bhe); MFMA_B(ao1, Al1[co], bho); \
    MFMA_B(ae0, Ah0[ce], ble); MFMA_B(ao0, Ah0[co], blo); \
    MFMA_B(ae1, Ah1[ce], ble); MFMA_B(ao1, Ah1[co], blo); \
  } \
  f32x16 s0v = ae0 + ao0, s1v = ae1 + ao1; \
  const float nv = nrm_g[(T)*32 + (l & 31)]; \
  const int colT = (T)*32 + (l & 31); \
  _Pragma("unroll") \
  for (int r = 0; r < 16; ++r) { \
    float c0 = fmaf(-2.f, s0v[r], nv); \
    if (c0 < bc0[r]) { bc0[r] = c0; bk0[r] = colT; } \
    float c1 = fmaf(-2.f, s1v[r], nv); \
    if (c1 < bc1[r]) { bc1[r] = c1; bk1[r] = colT; } } }

#define TILE_ITER(T) { \
  const int nxt = ((T)+1 < 30) ? (T)+1 : 29; \
  bf8v nh0 = Bph[nxt*512 + t];       bf8v nh1 = Bph[nxt*512 + 256 + t]; \
  bf8v nl0 = Bpl[nxt*512 + t];       bf8v nl1 = Bpl[nxt*512 + 256 + t]; \
  TILE_COMPUTE(T) \
  __syncthreads(); \
  BhL[t] = nh0; BhL[256 + t] = nh1; BlL[t] = nl0; BlL[256 + t] = nl1; \
  __syncthreads(); }

// lex-min argmin flush for one dict segment; reset running best
#define FLUSH(DICTID, BASE) { \
  _Pragma("unroll") \
  for (int r = 0; r < 16; ++r) { \
    float b0 = bc0[r]; int K0 = bk0[r]; float b1 = bc1[r]; int K1 = bk1[r]; \
    _Pragma("unroll") \
    for (int m = 1; m <= 16; m <<= 1) { \
      float pb = __shfl_xor(b0, m); int pk = __shfl_xor(K0, m); \
      if (pb < b0 || (pb == b0 && pk < K0)) { b0 = pb; K0 = pk; } \
      pb = __shfl_xor(b1, m); pk = __shfl_xor(K1, m); \
      if (pb < b1 || (pb == b1 && pk < K1)) { b1 = pb; K1 = pk; } } \
    if ((l & 31) == 0) { \
      const int ro = (r & 3) + 8 * (r >> 2) + 4 * hl; \
      keys[((rowbase + ro) << 2) | (DICTID)]      = K0 - (BASE); \
      keys[((rowbase + 32 + ro) << 2) | (DICTID)] = K1 - (BASE); } \
    bc0[r] = 1e30f; bk0[r] = 0; bc1[r] = 1e30f; bk1[r] = 0; } }

// ---- kernel 2: MFMA scoring. 256 blocks (1/CU), 4 waves x 64 rows ----
__global__ __launch_bounds__(256, 1) void vq_mfma(
    const float* __restrict__ x,
    const bf8v* __restrict__ Bph, const bf8v* __restrict__ Bpl,
    const float* __restrict__ nrm_g, int* __restrict__ keys)
{
  __shared__ float xlds[256 * 132];   // [row][c], pad 132 (16B-aligned rows) ~132 KB
  __shared__ bf8v  BhL[512];          // one 32-col tile, hi  (8 KB)
  __shared__ bf8v  BlL[512];          // lo (8 KB)

  const int t = threadIdx.x;
  const int w = t >> 6, l = t & 63;
  const int hl = l >> 5;
  const int rowbase = blockIdx.x * 256 + w * 64;

  // stage x slab (256 rows) fp32 -> LDS, coalesced
  {
    const float4* __restrict__ xg = (const float4*)x + (size_t)blockIdx.x * 8192;
    #pragma unroll
    for (int j = 0; j < 32; ++j) {
      const int f = j * 256 + t;
      const float4 v = xg[f];
      const int row = f >> 5, c4 = f & 31;
      *(float4*)&xlds[row * 132 + c4 * 4] = v;
    }
  }
  // prefetch B tile 0 while staging completes
  bf8v nh0 = Bph[t], nh1 = Bph[256 + t], nl0 = Bpl[t], nl1 = Bpl[256 + t];
  __syncthreads();

  // build A fragments: 2 row-tiles x 8 chunks, bf16 hi/lo, from LDS
  bf8v Ah0[8], Al0[8], Ah1[8], Al1[8];
  {
    const float* xr = xlds + (size_t)(w * 64 + (l & 31)) * 132;
    #pragma unroll
    for (int c = 0; c < 8; ++c) {
      const int k0 = c * 16 + hl * 8;
      float4 u0 = *(const float4*)(xr + k0);
      float4 u1 = *(const float4*)(xr + k0 + 4);
      MK8(u0, u1, Ah0[c], Al0[c])
      float4 v0 = *(const float4*)(xr + 32 * 132 + k0);
      float4 v1 = *(const float4*)(xr + 32 * 132 + k0 + 4);
      MK8(v0, v1, Ah1[c], Al1[c])
    }
  }
  // write B tile 0
  BhL[t] = nh0; BhL[256 + t] = nh1; BlL[t] = nl0; BlL[256 + t] = nl1;
  __syncthreads();

  f32x16 zero16;
  #pragma unroll
  for (int i = 0; i < 16; ++i) zero16[i] = 0.f;

  float bc0[16], bc1[16]; int bk0[16], bk1[16];
  #pragma unroll
  for (int r = 0; r < 16; ++r) { bc0[r] = 1e30f; bk0[r] = 0; bc1[r] = 1e30f; bk1[r] = 0; }

  // sweep col-tiles; dict boundaries at tiles {2,6,14,30}
  for (int T = 0;  T < 2;  ++T) TILE_ITER(T)
  FLUSH(0, 0)
  for (int T = 2;  T < 6;  ++T) TILE_ITER(T)
  FLUSH(1, 64)
  for (int T = 6;  T < 14; ++T) TILE_ITER(T)
  FLUSH(2, 192)
  for (int T = 14; T < 30; ++T) TILE_ITER(T)
  FLUSH(3, 448)
}

// ---- kernel 3: gather winners (coalesced via DT), write out + loss partials ----
__global__ __launch_bounds__(256, 8) void vq_merge(
    const float* __restrict__ x, const float* __restrict__ DT,
    const int* __restrict__ keys,
    const float* __restrict__ alpha_p, const float* __restrict__ gamma_p,
    float* __restrict__ out, float* __restrict__ partials)
{
  __shared__ int kk[2][4];
  __shared__ float wr[4];
  const int t = threadIdx.x;
  const int c = t & 127, rs = t >> 7;
  const int row0 = blockIdx.x * 2;
  if (t < 8) {
    int r = t >> 2, d = t & 3;
    kk[r][d] = keys[((row0 + r) << 2) | d];
  }
  __syncthreads();
  const int row = row0 + rs;
  const float a = alpha_p[0];
  const float g0 = gamma_p[0], g1 = gamma_p[1], g2 = gamma_p[2], g3 = gamma_p[3];
  const float xv = x[(size_t)row * CDIM + c];
  const float d0 = DT[         kk[rs][0] * 128 + c];
  const float d1 = DT[ 8192  + kk[rs][1] * 128 + c];
  const float d2 = DT[ 24576 + kk[rs][2] * 128 + c];
  const float d3 = DT[ 57344 + kk[rs][3] * 128 + c];
  out[(size_t)row * CDIM + c] = a * (g0*d0 + g1*d1 + g2*d2 + g3*d3);
  float e0 = fmaf(-a, d0, xv), e1 = fmaf(-a, d1, xv);
  float e2 = fmaf(-a, d2, xv), e3 = fmaf(-a, d3, xv);
  float lc = g0*e0*e0 + g1*e1*e1 + g2*e2*e2 + g3*e3*e3;
  #pragma unroll
  for (int off = 32; off > 0; off >>= 1) lc += __shfl_down(lc, off);
  if ((t & 63) == 0) wr[t >> 6] = lc;
  __syncthreads();
  if (t == 0) partials[blockIdx.x] = wr[0] + wr[1] + wr[2] + wr[3];
}

// ---- kernel 4: final deterministic loss reduction ----
__global__ void vq_loss(const float* __restrict__ partials, float* __restrict__ lossp) {
  __shared__ float wr[4];
  const int t = threadIdx.x;
  float v = 0.f;
  #pragma unroll 8
  for (int i = 0; i < 128; ++i) v += partials[i * 256 + t];
  #pragma unroll
  for (int off = 32; off > 0; off >>= 1) v += __shfl_down(v, off);
  if ((t & 63) == 0) wr[t >> 6] = v;
  __syncthreads();
  if (t == 0) lossp[0] = (wr[0] + wr[1] + wr[2] + wr[3]) * (1.25f / 8388608.f);
}

extern "C" void kernel_launch(void* const* d_in, const int* in_sizes, int n_in,
                              void* d_out, int out_size, void* d_ws, size_t ws_size,
                              hipStream_t stream) {
  const float* x  = (const float*)d_in[0];
  const float* D0 = (const float*)d_in[1];
  const float* D1 = (const float*)d_in[2];
  const float* D2 = (const float*)d_in[3];
  const float* D3 = (const float*)d_in[4];
  const float* alpha = (const float*)d_in[5];
  const float* gamma = (const float*)d_in[6];
  float* out = (float*)d_out;

  float* ws  = (float*)d_ws;
  float* nrm = ws;                         // 1024
  float* DT  = ws + 1024;                  // 122880
  bf8v*  Bph = (bf8v*)(ws + 123904);       // 61440 floats
  bf8v*  Bpl = (bf8v*)(ws + 185344);       // 61440 floats
  int*  keys = (int*)(ws + 246784);        // 262144 ints
  float* partials = ws + 508928;           // 32768

  vq_prep<<<4, 256, 0, stream>>>(D0, D1, D2, D3, nrm, DT);
  vq_pack<<<60, 256, 0, stream>>>(D0, D1, D2, D3, Bph, Bpl);
  vq_mfma<<<256, 256, 0, stream>>>(x, Bph, Bpl, nrm, keys);
  vq_merge<<<32768, 256, 0, stream>>>(x, DT, keys, alpha, gamma, out, partials);
  vq_loss<<<1, 256, 0, stream>>>(partials, out + NC);
}

// Round 11
// 144.346 us; speedup vs baseline: 1.9649x; 1.8357x over previous
//
#include <hip/hip_runtime.h>

#define CDIM 128
#define NC   8388608

typedef __attribute__((ext_vector_type(8)))  short bf8v;   // 8 bf16 (4 VGPRs)
typedef __attribute__((ext_vector_type(16))) float f32x16; // MFMA 32x32 acc

// ws layout (float offsets):
//   nrm  @0       (1024)
//   DT   @1024    (122880)
//   Bph  @123904  (61440)   [30 tiles][8 chunks][64 lanes] x 16B bf16-hi
//   Bpl  @185344  (61440)   same, bf16-lo
//   keys @246784  (262144 ints)
//   partials @508928 (32768)

__device__ __forceinline__ void bsplit(float v, short& h, short& lo) {
  unsigned u = __float_as_uint(v);
  unsigned hb = (u + 0x7fffu + ((u >> 16) & 1u)) >> 16;   // RNE to bf16
  float hf = __uint_as_float(hb << 16);
  float lf = v - hf;
  unsigned u2 = __float_as_uint(lf);
  unsigned lb = (u2 + 0x7fffu + ((u2 >> 16) & 1u)) >> 16;
  h = (short)hb; lo = (short)lb;
}

// ---- kernel 0: column norms + transposed fp32 dict copies (exact, for gather) ----
__global__ void vq_prep(const float* __restrict__ D0, const float* __restrict__ D1,
                        const float* __restrict__ D2, const float* __restrict__ D3,
                        float* __restrict__ nrm, float* __restrict__ DT) {
  int g = blockIdx.x * 256 + threadIdx.x;
  if (g >= 960) return;
  const float* D; int K, k; float* T;
  if (g < 64)       { D = D0; K = 64;  k = g;       T = DT; }
  else if (g < 192) { D = D1; K = 128; k = g - 64;  T = DT + 8192; }
  else if (g < 448) { D = D2; K = 256; k = g - 192; T = DT + 24576; }
  else              { D = D3; K = 512; k = g - 448; T = DT + 57344; }
  float s = 0.f;
  for (int c = 0; c < 128; ++c) { float v = D[c*K+k]; s = fmaf(v,v,s); T[k*128+c] = v; }
  nrm[g] = s;
}

// ---- kernel 1: pack dicts into MFMA B-fragment order, bf16 hi/lo ----
// entry g = (T*8 + c)*64 + lane: 8 bf16 = B[k0+j][col], col = T*32+(l&31), k0 = 16c+8*(l>>5)
__global__ void vq_pack(const float* __restrict__ D0, const float* __restrict__ D1,
                        const float* __restrict__ D2, const float* __restrict__ D3,
                        bf8v* __restrict__ Bph, bf8v* __restrict__ Bpl) {
  int g = blockIdx.x * 256 + threadIdx.x;           // 60*256 = 15360 exact
  int T = g >> 9, c = (g >> 6) & 7, l = g & 63;
  int col = T * 32 + (l & 31);
  int k0 = c * 16 + (l >> 5) * 8;
  const float* D; int K, cb;
  if (col < 64)       { D = D0; K = 64;  cb = col; }
  else if (col < 192) { D = D1; K = 128; cb = col - 64; }
  else if (col < 448) { D = D2; K = 256; cb = col - 192; }
  else                { D = D3; K = 512; cb = col - 448; }
  short h0,h1,h2,h3,h4,h5,h6,h7, q0,q1,q2,q3,q4,q5,q6,q7;
  bsplit(D[(k0+0)*K + cb], h0, q0);
  bsplit(D[(k0+1)*K + cb], h1, q1);
  bsplit(D[(k0+2)*K + cb], h2, q2);
  bsplit(D[(k0+3)*K + cb], h3, q3);
  bsplit(D[(k0+4)*K + cb], h4, q4);
  bsplit(D[(k0+5)*K + cb], h5, q5);
  bsplit(D[(k0+6)*K + cb], h6, q6);
  bsplit(D[(k0+7)*K + cb], h7, q7);
  Bph[g] = (bf8v){h0,h1,h2,h3,h4,h5,h6,h7};
  Bpl[g] = (bf8v){q0,q1,q2,q3,q4,q5,q6,q7};
}

#define MK8(U0, U1, HD, LD) { \
  short h0,h1,h2,h3,h4,h5,h6,h7, q0,q1,q2,q3,q4,q5,q6,q7; \
  bsplit(U0.x,h0,q0); bsplit(U0.y,h1,q1); bsplit(U0.z,h2,q2); bsplit(U0.w,h3,q3); \
  bsplit(U1.x,h4,q4); bsplit(U1.y,h5,q5); bsplit(U1.z,h6,q6); bsplit(U1.w,h7,q7); \
  HD = (bf8v){h0,h1,h2,h3,h4,h5,h6,h7}; \
  LD = (bf8v){q0,q1,q2,q3,q4,q5,q6,q7}; }

#define MFMA32(AC, AF, BF) AC = __builtin_amdgcn_mfma_f32_32x32x16_bf16((AF), (BF), (AC), 0, 0, 0)

// one 32-col tile: 16 coalesced B loads + 24 MFMAs + criterion (no LDS, no barriers)
#define TILE2(T) { \
  const bf8v* __restrict__ BhT = Bph + (T) * 512 + l; \
  const bf8v* __restrict__ BlT = Bpl + (T) * 512 + l; \
  f32x16 ae = zero16, ao = zero16; \
  _Pragma("unroll") \
  for (int cp = 0; cp < 4; ++cp) { \
    const int ce = 2*cp, co = 2*cp+1; \
    bf8v bhe = BhT[ce*64]; bf8v bho = BhT[co*64]; \
    bf8v ble = BlT[ce*64]; bf8v blo = BlT[co*64]; \
    MFMA32(ae, Ah[ce], bhe); MFMA32(ao, Ah[co], bho); \
    MFMA32(ae, Al[ce], bhe); MFMA32(ao, Al[co], bho); \
    MFMA32(ae, Ah[ce], ble); MFMA32(ao, Ah[co], blo); \
  } \
  f32x16 sv = ae + ao; \
  const float nv = nrm_g[(T)*32 + (l & 31)]; \
  const int colT = (T)*32 + (l & 31); \
  _Pragma("unroll") \
  for (int r = 0; r < 16; ++r) { \
    float c0 = fmaf(-2.f, sv[r], nv); \
    if (c0 < bc[r]) { bc[r] = c0; bk[r] = colT; } } }

// lex-min argmin flush for one dict segment; reset running best
#define FLUSH1(DICTID, BASE) { \
  _Pragma("unroll") \
  for (int r = 0; r < 16; ++r) { \
    float b0 = bc[r]; int K0 = bk[r]; \
    _Pragma("unroll") \
    for (int m = 1; m <= 16; m <<= 1) { \
      float pb = __shfl_xor(b0, m); int pk = __shfl_xor(K0, m); \
      if (pb < b0 || (pb == b0 && pk < K0)) { b0 = pb; K0 = pk; } } \
    if ((l & 31) == 0) { \
      const int ro = (r & 3) + 8 * (r >> 2) + 4 * hl; \
      keys[((rowbase + ro) << 2) | (DICTID)] = K0 - (BASE); } \
    bc[r] = 1e30f; bk[r] = 0; } }

// ---- kernel 2: MFMA scoring. 2048 single-wave blocks, 32 rows each, no LDS ----
__global__ __launch_bounds__(64, 2) void vq_mfma(
    const float* __restrict__ x,
    const bf8v* __restrict__ Bph, const bf8v* __restrict__ Bpl,
    const float* __restrict__ nrm_g, int* __restrict__ keys)
{
  const int l = threadIdx.x;
  const int hl = l >> 5;
  const int rowbase = blockIdx.x * 32;

  // A fragments straight from global: row = rowbase + (l&31), k0 = 16c + 8*hl
  bf8v Ah[8], Al[8];
  {
    const float* __restrict__ xr = x + (size_t)(rowbase + (l & 31)) * CDIM + hl * 8;
    #pragma unroll
    for (int c = 0; c < 8; ++c) {
      float4 u0 = *(const float4*)(xr + c * 16);
      float4 u1 = *(const float4*)(xr + c * 16 + 4);
      MK8(u0, u1, Ah[c], Al[c])
    }
  }

  f32x16 zero16;
  #pragma unroll
  for (int i = 0; i < 16; ++i) zero16[i] = 0.f;

  float bc[16]; int bk[16];
  #pragma unroll
  for (int r = 0; r < 16; ++r) { bc[r] = 1e30f; bk[r] = 0; }

  // sweep col-tiles; dict boundaries at tiles {2,6,14,30}
  for (int T = 0; T < 2; ++T) TILE2(T)
  FLUSH1(0, 0)
  #pragma unroll 2
  for (int T = 2; T < 6; ++T) TILE2(T)
  FLUSH1(1, 64)
  #pragma unroll 2
  for (int T = 6; T < 14; ++T) TILE2(T)
  FLUSH1(2, 192)
  #pragma unroll 2
  for (int T = 14; T < 30; ++T) TILE2(T)
  FLUSH1(3, 448)
}

// ---- kernel 3: gather winners (coalesced via DT), write out + loss partials ----
__global__ __launch_bounds__(256, 8) void vq_merge(
    const float* __restrict__ x, const float* __restrict__ DT,
    const int* __restrict__ keys,
    const float* __restrict__ alpha_p, const float* __restrict__ gamma_p,
    float* __restrict__ out, float* __restrict__ partials)
{
  __shared__ int kk[2][4];
  __shared__ float wr[4];
  const int t = threadIdx.x;
  const int c = t & 127, rs = t >> 7;
  const int row0 = blockIdx.x * 2;
  if (t < 8) {
    int r = t >> 2, d = t & 3;
    kk[r][d] = keys[((row0 + r) << 2) | d];
  }
  __syncthreads();
  const int row = row0 + rs;
  const float a = alpha_p[0];
  const float g0 = gamma_p[0], g1 = gamma_p[1], g2 = gamma_p[2], g3 = gamma_p[3];
  const float xv = x[(size_t)row * CDIM + c];
  const float d0 = DT[         kk[rs][0] * 128 + c];
  const float d1 = DT[ 8192  + kk[rs][1] * 128 + c];
  const float d2 = DT[ 24576 + kk[rs][2] * 128 + c];
  const float d3 = DT[ 57344 + kk[rs][3] * 128 + c];
  out[(size_t)row * CDIM + c] = a * (g0*d0 + g1*d1 + g2*d2 + g3*d3);
  float e0 = fmaf(-a, d0, xv), e1 = fmaf(-a, d1, xv);
  float e2 = fmaf(-a, d2, xv), e3 = fmaf(-a, d3, xv);
  float lc = g0*e0*e0 + g1*e1*e1 + g2*e2*e2 + g3*e3*e3;
  #pragma unroll
  for (int off = 32; off > 0; off >>= 1) lc += __shfl_down(lc, off);
  if ((t & 63) == 0) wr[t >> 6] = lc;
  __syncthreads();
  if (t == 0) partials[blockIdx.x] = wr[0] + wr[1] + wr[2] + wr[3];
}

// ---- kernel 4: final deterministic loss reduction ----
__global__ void vq_loss(const float* __restrict__ partials, float* __restrict__ lossp) {
  __shared__ float wr[4];
  const int t = threadIdx.x;
  float v = 0.f;
  #pragma unroll 8
  for (int i = 0; i < 128; ++i) v += partials[i * 256 + t];
  #pragma unroll
  for (int off = 32; off > 0; off >>= 1) v += __shfl_down(v, off);
  if ((t & 63) == 0) wr[t >> 6] = v;
  __syncthreads();
  if (t == 0) lossp[0] = (wr[0] + wr[1] + wr[2] + wr[3]) * (1.25f / 8388608.f);
}

extern "C" void kernel_launch(void* const* d_in, const int* in_sizes, int n_in,
                              void* d_out, int out_size, void* d_ws, size_t ws_size,
                              hipStream_t stream) {
  const float* x  = (const float*)d_in[0];
  const float* D0 = (const float*)d_in[1];
  const float* D1 = (const float*)d_in[2];
  const float* D2 = (const float*)d_in[3];
  const float* D3 = (const float*)d_in[4];
  const float* alpha = (const float*)d_in[5];
  const float* gamma = (const float*)d_in[6];
  float* out = (float*)d_out;

  float* ws  = (float*)d_ws;
  float* nrm = ws;                         // 1024
  float* DT  = ws + 1024;                  // 122880
  bf8v*  Bph = (bf8v*)(ws + 123904);       // 61440 floats
  bf8v*  Bpl = (bf8v*)(ws + 185344);       // 61440 floats
  int*  keys = (int*)(ws + 246784);        // 262144 ints
  float* partials = ws + 508928;           // 32768

  vq_prep<<<4, 256, 0, stream>>>(D0, D1, D2, D3, nrm, DT);
  vq_pack<<<60, 256, 0, stream>>>(D0, D1, D2, D3, Bph, Bpl);
  vq_mfma<<<2048, 64, 0, stream>>>(x, Bph, Bpl, nrm, keys);
  vq_merge<<<32768, 256, 0, stream>>>(x, DT, keys, alpha, gamma, out, partials);
  vq_loss<<<1, 256, 0, stream>>>(partials, out + NC);
}